// Round 9
// baseline (55.347 us; speedup 1.0000x reference)
//
#include <hip/hip_runtime.h>

// LocallyConnected2d: x(16,3,128,128) f32, W(61,61,64,3,8,8) f32, bias(64,61,61) f32
// out(16,1,488,488) f32; stride 2, kernel 8, no pad; pixel-shuffle r=8 epilogue.
//
// R7: LDS-free MFMA streaming. Per hw: C[16b x 64oc] = X[16x192].W[64x192]^T
// via mfma_f32_16x16x32_f16. Fragment loads go DIRECT global -> reg -> cvt ->
// MFMA: B-frag lane (lq,lk) reads W[oc][ks*32+lk*8..+8] = 32 B contiguous
// (4 lk-lanes = 128 B contiguous per oc row -> perfectly coalesced); A-frag
// k-run of 8 = one kernel-window row = 8 contiguous floats of x (8-B aligned
// -> float2 loads). No LDS, no barrier, no DS pipe at all; occupancy is
// VGPR-limited, every wave an independent W-streamer. W read exactly once;
// x read 4x per hw from L2. Block = 256 thr = 4 waves = one hw (wave wv ->
// ocs wv*16..+16). C: row(batch)=lk*4+r, col(oc)=lq (validated R6b).

namespace {
constexpr int NHW  = 61 * 61;       // 3721
constexpr int XB   = 3 * 128 * 128;
constexpr int XCC  = 128 * 128;
constexpr int OSTR = 488 * 488;
}

typedef __fp16   fp16x2 __attribute__((ext_vector_type(2)));
typedef _Float16 half8v __attribute__((ext_vector_type(8)));
typedef float    f32x4  __attribute__((ext_vector_type(4)));

union H8 { fp16x2 p[4]; half8v h; };

__global__ __launch_bounds__(256) void lc2d_kernel(
    const float* __restrict__ xg,   // [16][3][128][128]
    const float* __restrict__ wg,   // [61][61][64][3][8][8]
    const float* __restrict__ bg,   // [64][61][61]
    float* __restrict__ og)         // [16][488][488]
{
    const int hw   = blockIdx.x;
    const int h    = hw / 61;
    const int w    = hw - h * 61;
    const int t    = threadIdx.x;
    const int lane = t & 63;
    const int wv   = t >> 6;

    const int lq = lane & 15;       // A row (batch) / B row (oc within tile)
    const int lk = lane >> 4;       // k-run selector (8 floats)
    const int oc = wv * 16 + lq;    // global oc 0..63

    const float* wrow = wg + ((size_t)hw * 64 + oc) * 192;
    const float* xrow = xg + lq * XB + (h * 2) * 128 + (w * 2);

    f32x4 acc = {0.f, 0.f, 0.f, 0.f};

    #pragma unroll
    for (int ks = 0; ks < 6; ++ks) {
        const int k = ks * 32 + lk * 8;     // my 8-float run
        const int c = k >> 6;               // channel
        const int i = (k >> 3) & 7;         // kernel row
        const float* xs = xrow + c * XCC + i * 128;

        // x: 8 contiguous floats, 8-B aligned -> 4x float2
        const float2 x0 = *reinterpret_cast<const float2*>(xs);
        const float2 x1 = *reinterpret_cast<const float2*>(xs + 2);
        const float2 x2 = *reinterpret_cast<const float2*>(xs + 4);
        const float2 x3 = *reinterpret_cast<const float2*>(xs + 6);
        // W: 8 contiguous floats, 32-B aligned -> 2x float4
        const float4 w0 = *reinterpret_cast<const float4*>(wrow + k);
        const float4 w1 = *reinterpret_cast<const float4*>(wrow + k + 4);

        H8 av, bv;
        av.p[0] = __builtin_amdgcn_cvt_pkrtz(x0.x, x0.y);
        av.p[1] = __builtin_amdgcn_cvt_pkrtz(x1.x, x1.y);
        av.p[2] = __builtin_amdgcn_cvt_pkrtz(x2.x, x2.y);
        av.p[3] = __builtin_amdgcn_cvt_pkrtz(x3.x, x3.y);
        bv.p[0] = __builtin_amdgcn_cvt_pkrtz(w0.x, w0.y);
        bv.p[1] = __builtin_amdgcn_cvt_pkrtz(w0.z, w0.w);
        bv.p[2] = __builtin_amdgcn_cvt_pkrtz(w1.x, w1.y);
        bv.p[3] = __builtin_amdgcn_cvt_pkrtz(w1.z, w1.w);

        acc = __builtin_amdgcn_mfma_f32_16x16x32_f16(av.h, bv.h, acc, 0, 0, 0);
    }

    // ---- epilogue: bias + pixel-shuffle store
    const float bz = bg[oc * NHW + hw];
    float* ob = og + (h * 8 + (oc >> 3)) * 488 + (w * 8 + (oc & 7));
    #pragma unroll
    for (int r = 0; r < 4; ++r) {
        const int b = lk * 4 + r;           // batch = C row
        ob[(size_t)b * OSTR] = acc[r] + bz;
    }
}

extern "C" void kernel_launch(void* const* d_in, const int* in_sizes, int n_in,
                              void* d_out, int out_size, void* d_ws, size_t ws_size,
                              hipStream_t stream) {
    const float* x    = (const float*)d_in[0];
    const float* W    = (const float*)d_in[1];
    const float* bias = (const float*)d_in[2];
    float* out        = (float*)d_out;
    lc2d_kernel<<<dim3(NHW), dim3(256), 0, stream>>>(x, W, bias, out);
}

// Round 10
// 52.825 us; speedup vs baseline: 1.0477x; 1.0477x over previous
//
#include <hip/hip_runtime.h>

// LocallyConnected2d: x(16,3,128,128) f32, W(61,61,64,3,8,8) f32, bias(64,61,61) f32
// out(16,1,488,488) f32; stride 2, kernel 8, no pad; pixel-shuffle r=8 epilogue.
//
// R8: R7 (LDS-free MFMA streaming) + full W register prefetch + launch_bounds
// (256,4) so the compiler has 128 VGPRs/thread. R7's failure mode was
// VGPR_Count=32: loads issued in recycled-register batches -> serialized HBM
// latency. Here each thread issues its whole 48-float W slab (12x dwordx4,
// 48 VGPRs) as one independent batch up front, then x loads (L2-resident),
// then cvt+MFMA. Per-wave B-frag = 16 oc rows x 128 B contiguous; W read
// exactly once grid-wide. C: row(batch)=lk*4+r, col(oc)=lq (validated R6b/R7).

namespace {
constexpr int NHW  = 61 * 61;       // 3721
constexpr int XB   = 3 * 128 * 128;
constexpr int XCC  = 128 * 128;
constexpr int OSTR = 488 * 488;
}

typedef __fp16   fp16x2 __attribute__((ext_vector_type(2)));
typedef _Float16 half8v __attribute__((ext_vector_type(8)));
typedef float    f32x4  __attribute__((ext_vector_type(4)));

union H8 { fp16x2 p[4]; half8v h; };

__global__ __launch_bounds__(256, 4) void lc2d_kernel(
    const float* __restrict__ xg,   // [16][3][128][128]
    const float* __restrict__ wg,   // [61][61][64][3][8][8]
    const float* __restrict__ bg,   // [64][61][61]
    float* __restrict__ og)         // [16][488][488]
{
    const int hw   = blockIdx.x;
    const int h    = hw / 61;
    const int w    = hw - h * 61;
    const int t    = threadIdx.x;
    const int lane = t & 63;
    const int wv   = t >> 6;

    const int lq = lane & 15;       // A row (batch) / B row (oc within tile)
    const int lk = lane >> 4;       // k-run selector (8 floats)
    const int oc = wv * 16 + lq;    // global oc 0..63

    const float* wrow = wg + ((size_t)hw * 64 + oc) * 192;
    const float* xrow = xg + lq * XB + (h * 2) * 128 + (w * 2);

    // ---- prefetch the ENTIRE per-thread W slab: 12 independent dwordx4
    float4 wreg[12];
    #pragma unroll
    for (int ks = 0; ks < 6; ++ks) {
        const int k = ks * 32 + lk * 8;
        wreg[ks * 2]     = *reinterpret_cast<const float4*>(wrow + k);
        wreg[ks * 2 + 1] = *reinterpret_cast<const float4*>(wrow + k + 4);
    }

    // ---- prefetch all x runs (L2-resident after first block touches them)
    float2 xreg[24];
    #pragma unroll
    for (int ks = 0; ks < 6; ++ks) {
        const int k = ks * 32 + lk * 8;
        const int c = k >> 6;
        const int i = (k >> 3) & 7;
        const float* xs = xrow + c * XCC + i * 128;
        xreg[ks * 4]     = *reinterpret_cast<const float2*>(xs);
        xreg[ks * 4 + 1] = *reinterpret_cast<const float2*>(xs + 2);
        xreg[ks * 4 + 2] = *reinterpret_cast<const float2*>(xs + 4);
        xreg[ks * 4 + 3] = *reinterpret_cast<const float2*>(xs + 6);
    }

    f32x4 acc = {0.f, 0.f, 0.f, 0.f};
    #pragma unroll
    for (int ks = 0; ks < 6; ++ks) {
        H8 av, bv;
        av.p[0] = __builtin_amdgcn_cvt_pkrtz(xreg[ks*4].x,   xreg[ks*4].y);
        av.p[1] = __builtin_amdgcn_cvt_pkrtz(xreg[ks*4+1].x, xreg[ks*4+1].y);
        av.p[2] = __builtin_amdgcn_cvt_pkrtz(xreg[ks*4+2].x, xreg[ks*4+2].y);
        av.p[3] = __builtin_amdgcn_cvt_pkrtz(xreg[ks*4+3].x, xreg[ks*4+3].y);
        bv.p[0] = __builtin_amdgcn_cvt_pkrtz(wreg[ks*2].x,   wreg[ks*2].y);
        bv.p[1] = __builtin_amdgcn_cvt_pkrtz(wreg[ks*2].z,   wreg[ks*2].w);
        bv.p[2] = __builtin_amdgcn_cvt_pkrtz(wreg[ks*2+1].x, wreg[ks*2+1].y);
        bv.p[3] = __builtin_amdgcn_cvt_pkrtz(wreg[ks*2+1].z, wreg[ks*2+1].w);
        acc = __builtin_amdgcn_mfma_f32_16x16x32_f16(av.h, bv.h, acc, 0, 0, 0);
    }

    // ---- epilogue: bias + pixel-shuffle store
    const float bz = bg[oc * NHW + hw];
    float* ob = og + (h * 8 + (oc >> 3)) * 488 + (w * 8 + (oc & 7));
    #pragma unroll
    for (int r = 0; r < 4; ++r) {
        const int b = lk * 4 + r;           // batch = C row
        ob[(size_t)b * OSTR] = acc[r] + bz;
    }
}

extern "C" void kernel_launch(void* const* d_in, const int* in_sizes, int n_in,
                              void* d_out, int out_size, void* d_ws, size_t ws_size,
                              hipStream_t stream) {
    const float* x    = (const float*)d_in[0];
    const float* W    = (const float*)d_in[1];
    const float* bias = (const float*)d_in[2];
    float* out        = (float*)d_out;
    lc2d_kernel<<<dim3(NHW), dim3(256), 0, stream>>>(x, W, bias, out);
}

// Round 11
// 39.663 us; speedup vs baseline: 1.3954x; 1.3318x over previous
//
#include <hip/hip_runtime.h>

// LocallyConnected2d: x(16,3,128,128) f32, W(61,61,64,3,8,8) f32, bias(64,61,61) f32
// out(16,1,488,488) f32; stride 2, kernel 8, no pad; pixel-shuffle r=8 epilogue.
//
// R9: R6b (MFMA f16, LDS-staged, rotation-swizzled) with max memory-level
// parallelism: (1) load-ALL-then-convert staging -- each thread issues its 12
// W float4 + 6 x float2 as one independent batch (sched_barrier fence), so
// ~18 loads/thread are in flight instead of ~2; (2) one hw per 256-thread
// block (4 waves cover all 64 ocs; x staged once per hw); (3) LDS 30 KB ->
// 5 blocks/CU, 20 waves/CU via __launch_bounds__(256,5).
// Compute identical to validated R6b: rows of 24 8-f16 slots, slot s8 stored
// at (s8+row&7)%24 (2-way = free ds_read_b128); 6x mfma_f32_16x16x32_f16;
// C: row(batch)=lk*4+r, col(oc)=lq.

namespace {
constexpr int NHW  = 61 * 61;       // 3721
constexpr int XB   = 3 * 128 * 128;
constexpr int XCC  = 128 * 128;
constexpr int OSTR = 488 * 488;
}

typedef __fp16   fp16x2 __attribute__((ext_vector_type(2)));
typedef _Float16 half8v __attribute__((ext_vector_type(8)));
typedef float    f32x4  __attribute__((ext_vector_type(4)));

union H8 { fp16x2 p[4]; half8v h; uint4 u; };

__global__ __launch_bounds__(256, 5) void lc2d_kernel(
    const float* __restrict__ xg,   // [16][3][128][128]
    const float* __restrict__ wg,   // [61][61][64][3][8][8]
    const float* __restrict__ bg,   // [64][61][61]
    float* __restrict__ og)         // [16][488][488]
{
    __shared__ __align__(16) _Float16 wlh[64 * 192];   // 24 KB
    __shared__ __align__(16) _Float16 xlh[16 * 192];   //  6 KB

    const int hw   = blockIdx.x;
    const int h    = hw / 61;
    const int w    = hw - h * 61;
    const int t    = threadIdx.x;
    const int lane = t & 63;
    const int wv   = t >> 6;

    const float* wbase = wg + (size_t)hw * (64 * 192);
    const float* xb    = xg + (h * 2) * 128 + (w * 2);

    // ---- phase 1: issue ALL staging loads as one batch ------------------
    // W: 1536 groups of 8 floats; thread handles g = it*256+t, it<6.
    float4 wr[12];
    #pragma unroll
    for (int it = 0; it < 6; ++it) {
        const int g  = it * 256 + t;
        const int oc = g / 24;
        const int s8 = g - oc * 24;
        const float* src = wbase + oc * 192 + s8 * 8;
        wr[it * 2]     = *reinterpret_cast<const float4*>(src);
        wr[it * 2 + 1] = *reinterpret_cast<const float4*>(src + 4);
    }
    // x: 1536 float2; thread handles f = it*256+t, it<6.
    float2 xr[6];
    #pragma unroll
    for (int it = 0; it < 6; ++it) {
        const int f  = it * 256 + t;
        const int b  = f / 96;
        const int r  = f - b * 96;
        const int k  = r * 2;
        const int c  = k >> 6;              // channel
        const int i  = (k >> 3) & 7;        // kernel row
        const int j  = k & 7;               // within-run offset (even)
        xr[it] = *reinterpret_cast<const float2*>(xb + b * XB + c * XCC + i * 128 + j);
    }
    __builtin_amdgcn_sched_barrier(0);      // keep the whole batch in flight

    // ---- phase 2: convert + LDS write -----------------------------------
    #pragma unroll
    for (int it = 0; it < 6; ++it) {
        const int g  = it * 256 + t;
        const int oc = g / 24;
        const int s8 = g - oc * 24;
        H8 u;
        u.p[0] = __builtin_amdgcn_cvt_pkrtz(wr[it*2].x,   wr[it*2].y);
        u.p[1] = __builtin_amdgcn_cvt_pkrtz(wr[it*2].z,   wr[it*2].w);
        u.p[2] = __builtin_amdgcn_cvt_pkrtz(wr[it*2+1].x, wr[it*2+1].y);
        u.p[3] = __builtin_amdgcn_cvt_pkrtz(wr[it*2+1].z, wr[it*2+1].w);
        int srot = s8 + (oc & 7); if (srot >= 24) srot -= 24;
        *reinterpret_cast<uint4*>(&wlh[oc * 192 + srot * 8]) = u.u;
    }
    #pragma unroll
    for (int it = 0; it < 6; ++it) {
        const int f  = it * 256 + t;
        const int b  = f / 96;
        const int r  = f - b * 96;
        const int s8 = r >> 2;
        const int j  = (r & 3) * 2;
        const fp16x2 pk = __builtin_amdgcn_cvt_pkrtz(xr[it].x, xr[it].y);
        int srot = s8 + (b & 7); if (srot >= 24) srot -= 24;
        union { fp16x2 p; unsigned u; } cv; cv.p = pk;
        *reinterpret_cast<unsigned*>(&xlh[b * 192 + srot * 8 + j]) = cv.u;
    }
    __syncthreads();

    // ---- phase 3: MFMA (wave wv -> ocs wv*16..+16) ----------------------
    const int lq  = lane & 15;          // A row (batch) / B col (oc)
    const int lk  = lane >> 4;          // k-run selector
    const int ocl = wv * 16 + lq;

    f32x4 acc = {0.f, 0.f, 0.f, 0.f};
    #pragma unroll
    for (int ks = 0; ks < 6; ++ks) {
        const int slog = ks * 4 + lk;
        int sa = slog + (lq & 7);   if (sa >= 24) sa -= 24;
        int sb = slog + (ocl & 7);  if (sb >= 24) sb -= 24;
        const half8v av = *reinterpret_cast<const half8v*>(&xlh[lq  * 192 + sa * 8]);
        const half8v bv = *reinterpret_cast<const half8v*>(&wlh[ocl * 192 + sb * 8]);
        acc = __builtin_amdgcn_mfma_f32_16x16x32_f16(av, bv, acc, 0, 0, 0);
    }

    // ---- epilogue: bias + pixel-shuffle store ---------------------------
    const float bz = bg[ocl * NHW + hw];
    float* ob = og + (h * 8 + (ocl >> 3)) * 488 + (w * 8 + (ocl & 7));
    #pragma unroll
    for (int r = 0; r < 4; ++r) {
        const int b = lk * 4 + r;       // batch = C row
        ob[(size_t)b * OSTR] = acc[r] + bz;
    }
}

extern "C" void kernel_launch(void* const* d_in, const int* in_sizes, int n_in,
                              void* d_out, int out_size, void* d_ws, size_t ws_size,
                              hipStream_t stream) {
    const float* x    = (const float*)d_in[0];
    const float* W    = (const float*)d_in[1];
    const float* bias = (const float*)d_in[2];
    float* out        = (float*)d_out;
    lc2d_kernel<<<dim3(NHW), dim3(256), 0, stream>>>(x, W, bias, out);
}